// Round 16
// baseline (85.669 us; speedup 1.0000x reference)
//
#include <hip/hip_runtime.h>

#define T_DIM 256
#define C_DIM 384
#define H_DIM 64

typedef __attribute__((ext_vector_type(4))) float f32x4;
typedef __attribute__((ext_vector_type(8))) short bf16x8;
typedef unsigned short u16;

// fp32 -> bf16 round-to-nearest-even (finite inputs)
__device__ __forceinline__ u16 f2b(float f) {
  unsigned u = __float_as_uint(f);
  u = (u + 0x7FFFu + ((u >> 16) & 1u)) >> 16;
  return (u16)u;
}
// packed f32x2 -> bf16x2: lo word = bf16(a), hi word = bf16(b)  (HW-verified)
__device__ __forceinline__ unsigned pkbf(float a, float b) {
  unsigned r;
  asm("v_cvt_pk_bf16_f32 %0, %1, %2" : "=v"(r) : "v"(a), "v"(b));
  return r;
}

// Swizzled element offsets (u16 units). Writes and reads share the permutation.
__device__ __forceinline__ int sw64(int r, int c)  { return r * 64  + (c ^ ((r & 7) << 3)); }
__device__ __forceinline__ int sw256(int h, int t) { return h * 256 + (t ^ ((h & 7) << 3)); }
__device__ __forceinline__ int sw32(int r, int c)  { return r * 32  + (c ^ (((r >> 1) & 3) << 3)); }

// ===================== K1: QKV GEMM -> ws (bf16) =====================
// R8's proven phase-1 staging/MFMA structure (1024 thr, 16 waves, K-step 32),
// epilogue writes q[256][64], k[256][64], vT[64][256] bf16 per batch.
// Pure streaming: no phase transition, blocks pipeline back-to-back.
__global__ __launch_bounds__(1024)
void qkv_k(const float* __restrict__ x,
           const float* __restrict__ Wk,
           const float* __restrict__ Wq,
           const float* __restrict__ Wv,
           u16* __restrict__ qkv, int b0)
{
  __shared__ u16 sh[16384];   // 32 KB: xs [256][32] sw32 @0; wsT [192][32] sw32 @8192
  u16* xs  = sh;
  u16* wsT = sh + 8192;

  const int tid  = threadIdx.x;
  const int wv   = tid >> 6;     // 0..15
  const int lane = tid & 63;
  const int g    = lane >> 4;
  const int lr   = lane & 15;
  const int b    = b0 + blockIdx.x;

  const float* xb = x + (size_t)b * (T_DIM * C_DIM);

  // x staging: 2048 uint2-groups (4 floats) per K-chunk, 2 per thread
  int xr[2], xc[2];
#pragma unroll
  for (int it = 0; it < 2; ++it) {
    int idx = tid + it * 1024;
    xr[it] = idx >> 3;
    xc[it] = (idx & 7) * 4;
  }
  // W staging: 1536 tasks (row-quad q = idx>>5, col cc = idx&31, lane-consecutive)
  int wrow[2], wcc[2];
  const float* wsrc[2];
  bool wok[2];
#pragma unroll
  for (int it = 0; it < 2; ++it) {
    int idx = tid + it * 1024;
    wok[it] = (idx < 1536);
    int q   = (idx >> 5) & 63;
    int cc  = idx & 31;
    int seg = q >> 4;
    int hq  = q & 15;
    wrow[it] = seg * 64 + hq * 4;
    wcc[it]  = cc;
    wsrc[it] = ((seg == 0) ? Wq : (seg == 1) ? Wk : Wv) + hq * 4;
  }

  f32x4 acc[12];
#pragma unroll
  for (int nj = 0; nj < 12; ++nj)
    acc[nj] = (f32x4){0.f, 0.f, 0.f, 0.f};

  f32x4 px[2], pwv[2];
#pragma unroll
  for (int it = 0; it < 2; ++it)
    px[it] = *reinterpret_cast<const f32x4*>(xb + xr[it] * C_DIM + xc[it]);
#pragma unroll
  for (int it = 0; it < 2; ++it)
    if (wok[it])
      pwv[it] = *reinterpret_cast<const f32x4*>(wsrc[it] + wcc[it] * H_DIM);

  for (int kt = 0; kt < 12; ++kt) {
    __syncthreads();
#pragma unroll
    for (int it = 0; it < 2; ++it) {
      uint2 pv;
      pv.x = pkbf(px[it][0], px[it][1]);
      pv.y = pkbf(px[it][2], px[it][3]);
      *reinterpret_cast<uint2*>(&xs[sw32(xr[it], xc[it])]) = pv;
    }
#pragma unroll
    for (int it = 0; it < 2; ++it)
      if (wok[it]) {
        wsT[sw32(wrow[it] + 0, wcc[it])] = f2b(pwv[it][0]);
        wsT[sw32(wrow[it] + 1, wcc[it])] = f2b(pwv[it][1]);
        wsT[sw32(wrow[it] + 2, wcc[it])] = f2b(pwv[it][2]);
        wsT[sw32(wrow[it] + 3, wcc[it])] = f2b(pwv[it][3]);
      }
    if (kt < 11) {
      int kk = (kt + 1) * 32;
#pragma unroll
      for (int it = 0; it < 2; ++it)
        px[it] = *reinterpret_cast<const f32x4*>(xb + xr[it] * C_DIM + kk + xc[it]);
#pragma unroll
      for (int it = 0; it < 2; ++it)
        if (wok[it])
          pwv[it] = *reinterpret_cast<const f32x4*>(wsrc[it] + (kk + wcc[it]) * H_DIM);
    }
    __syncthreads();

    bf16x8 afr = *reinterpret_cast<const bf16x8*>(&xs[sw32(wv * 16 + lr, g * 8)]);
#pragma unroll
    for (int nj = 0; nj < 12; ++nj) {
      bf16x8 bfr = *reinterpret_cast<const bf16x8*>(&wsT[sw32(nj * 16 + lr, g * 8)]);
      acc[nj] = __builtin_amdgcn_mfma_f32_16x16x32_bf16(afr, bfr, acc[nj], 0, 0, 0);
    }
  }

  // epilogue: write q,k,vT bf16 to ws. D layout: value(nj,e) = QKV[16wv+4g+e][16nj+lr].
  u16* qb = qkv + (size_t)b * 49152;   // q[256][64]
  u16* kb = qb + 16384;                // k[256][64]
  u16* vb = qb + 32768;                // vT[64][256]
  const int r0 = wv * 16 + g * 4;
#pragma unroll
  for (int nj = 0; nj < 4; ++nj)
#pragma unroll
    for (int e = 0; e < 4; ++e)
      qb[(r0 + e) * 64 + nj * 16 + lr] = f2b(acc[nj][e]);
#pragma unroll
  for (int nj = 4; nj < 8; ++nj)
#pragma unroll
    for (int e = 0; e < 4; ++e)
      kb[(r0 + e) * 64 + (nj - 4) * 16 + lr] = f2b(acc[nj][e]);
#pragma unroll
  for (int nj = 8; nj < 12; ++nj) {
    uint2 pv;
    pv.x = pkbf(acc[nj][0], acc[nj][1]);
    pv.y = pkbf(acc[nj][2], acc[nj][3]);
    *reinterpret_cast<uint2*>(&vb[((nj - 8) * 16 + lr) * 256 + r0]) = pv;
  }
}

// ===================== K2: causal flash attention from ws =====================
// 512 thr, 8 waves, wave wv owns rows [32wv,32wv+32). R12-proven phase 2.
// K/V staged to LDS via coalesced 16B copies; Q B-fragments direct from ws.
__global__ __launch_bounds__(512, 2)
void attn_k(const u16* __restrict__ qkv, float* __restrict__ out, int b0)
{
  __shared__ u16 sh[32768];   // ks [256][64] sw64 @0; vT [64][256] sw256 @16384
  u16* ks = sh;
  u16* vT = sh + 16384;

  const int tid  = threadIdx.x;
  const int wv   = tid >> 6;
  const int lane = tid & 63;
  const int g    = lane >> 4;
  const int lr   = lane & 15;
  const int b    = b0 + blockIdx.x;

  const u16* qb = qkv + (size_t)b * 49152;
  const u16* kg = qb + 16384;
  const u16* vg = qb + 32768;

  // stage K [256][64]: 2048 16B tasks, 4/thread; sw64 spreads row-groups -> 2 lanes/bank
#pragma unroll
  for (int it = 0; it < 4; ++it) {
    int idx = tid + it * 512;
    int r = idx >> 3, c = (idx & 7) * 8;
    *reinterpret_cast<uint4*>(&ks[sw64(r, c)]) =
        *reinterpret_cast<const uint4*>(&kg[r * 64 + c]);
  }
  // stage vT [64][256]
#pragma unroll
  for (int it = 0; it < 4; ++it) {
    int idx = tid + it * 512;
    int h = idx >> 5, t = (idx & 31) * 8;
    *reinterpret_cast<uint4*>(&vT[sw256(h, t)]) =
        *reinterpret_cast<const uint4*>(&vg[h * 256 + t]);
  }
  // Q B-fragments direct from ws: qf[mi][kb][e] = Q[32wv+16mi+lr][32kb+8g+e]
  bf16x8 qf[2][2];
#pragma unroll
  for (int mi = 0; mi < 2; ++mi)
#pragma unroll
    for (int kb = 0; kb < 2; ++kb)
      qf[mi][kb] = *reinterpret_cast<const bf16x8*>(
          &qb[(wv * 32 + mi * 16 + lr) * 64 + kb * 32 + g * 8]);
  __syncthreads();

  const int r0   = wv * 32;
  const int jmax = wv >> 1;

  f32x4 o[2][4];
  float m_run[2], l_run[2];
#pragma unroll
  for (int mi = 0; mi < 2; ++mi) {
    m_run[mi] = -__builtin_inff();
    l_run[mi] = 0.f;
#pragma unroll
    for (int nh = 0; nh < 4; ++nh) o[mi][nh] = (f32x4){0.f, 0.f, 0.f, 0.f};
  }

  for (int j = 0; j <= jmax; ++j) {
    f32x4 sT[2][4];
#pragma unroll
    for (int mi = 0; mi < 2; ++mi)
#pragma unroll
      for (int ni = 0; ni < 4; ++ni)
        sT[mi][ni] = (f32x4){0.f, 0.f, 0.f, 0.f};
#pragma unroll
    for (int kb = 0; kb < 2; ++kb) {
#pragma unroll
      for (int ni = 0; ni < 4; ++ni) {
        bf16x8 kf = *reinterpret_cast<const bf16x8*>(&ks[sw64(j * 64 + ni * 16 + lr, kb * 32 + g * 8)]);
#pragma unroll
        for (int mi = 0; mi < 2; ++mi)
          sT[mi][ni] = __builtin_amdgcn_mfma_f32_16x16x32_bf16(kf, qf[mi][kb], sT[mi][ni], 0, 0, 0);
      }
    }

#pragma unroll
    for (int mi = 0; mi < 2; ++mi) {
      const int q = r0 + mi * 16 + lr;
      float pm = -__builtin_inff();
#pragma unroll
      for (int ni = 0; ni < 4; ++ni)
#pragma unroll
        for (int e = 0; e < 4; ++e) {
          float v = sT[mi][ni][e] * 0.125f;
          int kv = j * 64 + ni * 16 + g * 4 + e;
          v = (kv > q) ? -__builtin_inff() : v;
          sT[mi][ni][e] = v;
          pm = fmaxf(pm, v);
        }
      pm = fmaxf(pm, __shfl_xor(pm, 16));
      pm = fmaxf(pm, __shfl_xor(pm, 32));

      float mn = fmaxf(m_run[mi], pm);
      float alpha = __expf(m_run[mi] - mn);
      m_run[mi] = mn;
      float rs = 0.f;
#pragma unroll
      for (int ni = 0; ni < 4; ++ni)
#pragma unroll
        for (int e = 0; e < 4; ++e) {
          float p = __expf(sT[mi][ni][e] - mn);
          sT[mi][ni][e] = p;
          rs += p;
        }
      rs += __shfl_xor(rs, 16);
      rs += __shfl_xor(rs, 32);
      l_run[mi] = l_run[mi] * alpha + rs;

#pragma unroll
      for (int e = 0; e < 4; ++e) {
        float am = __shfl(alpha, g * 4 + e);
#pragma unroll
        for (int nh = 0; nh < 4; ++nh) o[mi][nh][e] *= am;
      }
    }

    union PA { unsigned w[4]; bf16x8 v; };
    PA pa[2][2];
#pragma unroll
    for (int mi = 0; mi < 2; ++mi) {
      unsigned pk[4][2];
#pragma unroll
      for (int ni = 0; ni < 4; ++ni) {
        pk[ni][0] = pkbf(sT[mi][ni][0], sT[mi][ni][1]);
        pk[ni][1] = pkbf(sT[mi][ni][2], sT[mi][ni][3]);
      }
#pragma unroll
      for (int kb = 0; kb < 2; ++kb)
#pragma unroll
        for (int w = 0; w < 4; ++w) {
          int sl = ((2 * g + (w >> 1)) & 3) * 16 + lr;
          unsigned lo = __shfl(pk[2 * kb + 0][w & 1], sl);
          unsigned hi = __shfl(pk[2 * kb + 1][w & 1], sl);
          pa[mi][kb].w[w] = (g >= 2) ? hi : lo;
        }
    }

#pragma unroll
    for (int kb = 0; kb < 2; ++kb) {
#pragma unroll
      for (int nh = 0; nh < 4; ++nh) {
        bf16x8 vf = *reinterpret_cast<const bf16x8*>(&vT[sw256(nh * 16 + lr, j * 64 + kb * 32 + g * 8)]);
#pragma unroll
        for (int mi = 0; mi < 2; ++mi)
          o[mi][nh] = __builtin_amdgcn_mfma_f32_16x16x32_bf16(pa[mi][kb].v, vf, o[mi][nh], 0, 0, 0);
      }
    }
  }

  float* ob = out + (size_t)b * (T_DIM * H_DIM);
#pragma unroll
  for (int mi = 0; mi < 2; ++mi) {
    float linv[4];
#pragma unroll
    for (int e = 0; e < 4; ++e)
      linv[e] = 1.f / __shfl(l_run[mi], g * 4 + e);
#pragma unroll
    for (int nh = 0; nh < 4; ++nh)
#pragma unroll
      for (int e = 0; e < 4; ++e) {
        int r = r0 + mi * 16 + g * 4 + e;
        int h = nh * 16 + lr;
        ob[r * H_DIM + h] = o[mi][nh][e] * linv[e];
      }
  }
}

// ===================== Fallback: R8 fused (59.7 us proven) =====================
__global__ __launch_bounds__(1024, 4)
void head_fused(const float* __restrict__ x,
                const float* __restrict__ Wk,
                const float* __restrict__ Wq,
                const float* __restrict__ Wv,
                float* __restrict__ out)
{
  __shared__ u16 sh[32768];
  u16* xs  = sh;
  u16* wsT = sh + 8192;
  u16* ks  = sh;
  u16* vT  = sh + 16384;

  const int tid  = threadIdx.x;
  const int wv   = tid >> 6;
  const int lane = tid & 63;
  const int g    = lane >> 4;
  const int lr   = lane & 15;
  const int b    = blockIdx.x;

  const float* xb = x + (size_t)b * (T_DIM * C_DIM);

  int xr[2], xc[2];
#pragma unroll
  for (int it = 0; it < 2; ++it) {
    int idx = tid + it * 1024;
    xr[it] = idx >> 3;
    xc[it] = (idx & 7) * 4;
  }
  int wrow[2], wcc[2];
  const float* wsrc[2];
  bool wok[2];
#pragma unroll
  for (int it = 0; it < 2; ++it) {
    int idx = tid + it * 1024;
    wok[it] = (idx < 1536);
    int q   = (idx >> 5) & 63;
    int cc  = idx & 31;
    int seg = q >> 4;
    int hq  = q & 15;
    wrow[it] = seg * 64 + hq * 4;
    wcc[it]  = cc;
    wsrc[it] = ((seg == 0) ? Wq : (seg == 1) ? Wk : Wv) + hq * 4;
  }

  f32x4 acc[12];
#pragma unroll
  for (int nj = 0; nj < 12; ++nj)
    acc[nj] = (f32x4){0.f, 0.f, 0.f, 0.f};

  f32x4 px[2], pwv[2];
#pragma unroll
  for (int it = 0; it < 2; ++it)
    px[it] = *reinterpret_cast<const f32x4*>(xb + xr[it] * C_DIM + xc[it]);
#pragma unroll
  for (int it = 0; it < 2; ++it)
    if (wok[it])
      pwv[it] = *reinterpret_cast<const f32x4*>(wsrc[it] + wcc[it] * H_DIM);

  for (int kt = 0; kt < 12; ++kt) {
    __syncthreads();
#pragma unroll
    for (int it = 0; it < 2; ++it) {
      uint2 pv;
      pv.x = pkbf(px[it][0], px[it][1]);
      pv.y = pkbf(px[it][2], px[it][3]);
      *reinterpret_cast<uint2*>(&xs[sw32(xr[it], xc[it])]) = pv;
    }
#pragma unroll
    for (int it = 0; it < 2; ++it)
      if (wok[it]) {
        wsT[sw32(wrow[it] + 0, wcc[it])] = f2b(pwv[it][0]);
        wsT[sw32(wrow[it] + 1, wcc[it])] = f2b(pwv[it][1]);
        wsT[sw32(wrow[it] + 2, wcc[it])] = f2b(pwv[it][2]);
        wsT[sw32(wrow[it] + 3, wcc[it])] = f2b(pwv[it][3]);
      }
    if (kt < 11) {
      int kk = (kt + 1) * 32;
#pragma unroll
      for (int it = 0; it < 2; ++it)
        px[it] = *reinterpret_cast<const f32x4*>(xb + xr[it] * C_DIM + kk + xc[it]);
#pragma unroll
      for (int it = 0; it < 2; ++it)
        if (wok[it])
          pwv[it] = *reinterpret_cast<const f32x4*>(wsrc[it] + (kk + wcc[it]) * H_DIM);
    }
    __syncthreads();

    bf16x8 afr = *reinterpret_cast<const bf16x8*>(&xs[sw32(wv * 16 + lr, g * 8)]);
#pragma unroll
    for (int nj = 0; nj < 12; ++nj) {
      bf16x8 bfr = *reinterpret_cast<const bf16x8*>(&wsT[sw32(nj * 16 + lr, g * 8)]);
      acc[nj] = __builtin_amdgcn_mfma_f32_16x16x32_bf16(afr, bfr, acc[nj], 0, 0, 0);
    }
  }

  __syncthreads();
  u16* slab = sh + wv * 1024;
#pragma unroll
  for (int nj = 0; nj < 4; ++nj)
#pragma unroll
    for (int e = 0; e < 4; ++e)
      slab[sw64(g * 4 + e, nj * 16 + lr)] = f2b(acc[nj][e]);
  asm volatile("s_waitcnt lgkmcnt(0)" ::: "memory");

  bf16x8 qf[2];
#pragma unroll
  for (int kb = 0; kb < 2; ++kb)
    qf[kb] = *reinterpret_cast<const bf16x8*>(&slab[sw64(lr, kb * 32 + g * 8)]);
  __syncthreads();

#pragma unroll
  for (int nj = 4; nj < 12; ++nj)
#pragma unroll
    for (int e = 0; e < 4; ++e) {
      int r = wv * 16 + g * 4 + e;
      int n = nj * 16 + lr;
      u16 val = f2b(acc[nj][e]);
      if (n < 128) ks[sw64(r, n - 64)] = val;
      else         vT[sw256(n - 128, r)] = val;
    }
  __syncthreads();

  const int r0   = wv * 16;
  const int jmax = wv >> 2;

  f32x4 o[4];
  float m_run = -__builtin_inff(), l_run = 0.f;
#pragma unroll
  for (int nh = 0; nh < 4; ++nh) o[nh] = (f32x4){0.f, 0.f, 0.f, 0.f};

  for (int j = 0; j <= jmax; ++j) {
    f32x4 sT[4];
#pragma unroll
    for (int ni = 0; ni < 4; ++ni) sT[ni] = (f32x4){0.f, 0.f, 0.f, 0.f};
#pragma unroll
    for (int kb = 0; kb < 2; ++kb) {
#pragma unroll
      for (int ni = 0; ni < 4; ++ni) {
        bf16x8 kf = *reinterpret_cast<const bf16x8*>(&ks[sw64(j * 64 + ni * 16 + lr, kb * 32 + g * 8)]);
        sT[ni] = __builtin_amdgcn_mfma_f32_16x16x32_bf16(kf, qf[kb], sT[ni], 0, 0, 0);
      }
    }

    const int q = r0 + lr;
    float pm = -__builtin_inff();
#pragma unroll
    for (int ni = 0; ni < 4; ++ni)
#pragma unroll
      for (int e = 0; e < 4; ++e) {
        float v = sT[ni][e] * 0.125f;
        int kv = j * 64 + ni * 16 + g * 4 + e;
        v = (kv > q) ? -__builtin_inff() : v;
        sT[ni][e] = v;
        pm = fmaxf(pm, v);
      }
    pm = fmaxf(pm, __shfl_xor(pm, 16));
    pm = fmaxf(pm, __shfl_xor(pm, 32));

    float mn = fmaxf(m_run, pm);
    float alpha = __expf(m_run - mn);
    m_run = mn;
    float rs = 0.f;
#pragma unroll
    for (int ni = 0; ni < 4; ++ni)
#pragma unroll
      for (int e = 0; e < 4; ++e) {
        float p = __expf(sT[ni][e] - mn);
        sT[ni][e] = p;
        rs += p;
      }
    rs += __shfl_xor(rs, 16);
    rs += __shfl_xor(rs, 32);
    l_run = l_run * alpha + rs;

#pragma unroll
    for (int e = 0; e < 4; ++e) {
      float am = __shfl(alpha, g * 4 + e);
#pragma unroll
      for (int nh = 0; nh < 4; ++nh) o[nh][e] *= am;
    }

    union PA { unsigned w[4]; bf16x8 v; };
    PA pa[2];
    unsigned pk[4][2];
#pragma unroll
    for (int ni = 0; ni < 4; ++ni) {
      pk[ni][0] = pkbf(sT[ni][0], sT[ni][1]);
      pk[ni][1] = pkbf(sT[ni][2], sT[ni][3]);
    }
#pragma unroll
    for (int kb = 0; kb < 2; ++kb)
#pragma unroll
      for (int w = 0; w < 4; ++w) {
        int sl = ((2 * g + (w >> 1)) & 3) * 16 + lr;
        unsigned lo = __shfl(pk[2 * kb + 0][w & 1], sl);
        unsigned hi = __shfl(pk[2 * kb + 1][w & 1], sl);
        pa[kb].w[w] = (g >= 2) ? hi : lo;
      }

#pragma unroll
    for (int kb = 0; kb < 2; ++kb) {
#pragma unroll
      for (int nh = 0; nh < 4; ++nh) {
        bf16x8 vf = *reinterpret_cast<const bf16x8*>(&vT[sw256(nh * 16 + lr, j * 64 + kb * 32 + g * 8)]);
        o[nh] = __builtin_amdgcn_mfma_f32_16x16x32_bf16(pa[kb].v, vf, o[nh], 0, 0, 0);
      }
    }
  }

  float* ob = out + (size_t)b * (T_DIM * H_DIM);
  float linv[4];
#pragma unroll
  for (int e = 0; e < 4; ++e)
    linv[e] = 1.f / __shfl(l_run, g * 4 + e);
#pragma unroll
  for (int nh = 0; nh < 4; ++nh)
#pragma unroll
    for (int e = 0; e < 4; ++e) {
      int r = r0 + g * 4 + e;
      int h = nh * 16 + lr;
      ob[r * H_DIM + h] = o[nh][e] * linv[e];
    }
}

extern "C" void kernel_launch(void* const* d_in, const int* in_sizes, int n_in,
                              void* d_out, int out_size, void* d_ws, size_t ws_size,
                              hipStream_t stream) {
  const float* x  = (const float*)d_in[0];
  const float* Wk = (const float*)d_in[1];
  const float* Wq = (const float*)d_in[2];
  const float* Wv = (const float*)d_in[3];
  float* out = (float*)d_out;
  int B = in_sizes[0] / (T_DIM * C_DIM);   // 512

  const size_t per_b = 49152 * sizeof(u16);   // 96 KB/batch in ws
  if (ws_size >= 128 * per_b) {
    int slice = B;
    while ((size_t)slice * per_b > ws_size) slice >>= 1;   // power-of-2; B=512
    u16* qkv = (u16*)d_ws;
    for (int b0 = 0; b0 < B; b0 += slice) {
      int n = (B - b0 < slice) ? (B - b0) : slice;
      qkv_k<<<dim3(n), dim3(1024), 0, stream>>>(x, Wk, Wq, Wv, qkv, b0);
      attn_k<<<dim3(n), dim3(512), 0, stream>>>(qkv, out, b0);
    }
  } else {
    // ws too small for the split path: proven fused kernel (59.7 us)
    head_fused<<<dim3(B), dim3(1024), 0, stream>>>(x, Wk, Wq, Wv, out);
  }
}